// Round 7
// baseline (183.664 us; speedup 1.0000x reference)
//
#include <hip/hip_runtime.h>
#include <hip/hip_bf16.h>

// PairRE scoring: out[b,n] = -|| t_hat[n]*rt[b] - h_hat[b]*rh[b] ||_2
// B=512, N=2048, E=256.
//
// Reformulation WITHOUT tail normalization in operands:
//   S1(b,n) = sum_e (rt^2)_b[e] * (t^2)_n[e]
//   S2(b,n) = sum_e (-2*rt*Hh)_b[e] * t_n[e],   Hh = (h/||h||)*rh
//   x = S1*invt^2 + S2*invt + c_b,  invt = 1/max(||t||,eps), c_b = ||Hh_b||^2
//   out = -sqrt(max(x,0))
//
// R7: ONE ordinary kernel (graph-capturable), 512 blocks (32b x 64n tiles).
//  * Tail side: block-local. Raw t -> LDS bf16 frags [t^2 | t] (coalesced
//    reads; frag writes are a lane permutation of stride-1 = conflict-free);
//    per-row ||t||^2 via 2 adjacent-lane shfls.
//  * Head side (shared, tiny): blocks 0..31 each build one 16-row packed
//    A-group ([rt^2 | -2*rt*Hh] frags, verified R3/R4 layout) + cvec in ws,
//    then threadfence + release-flag. Producers never wait => deadlock-free.
//    Consumers acquire-spin (bounded guard -> never hangs).
//  * Flags: MAGIC != 0xAAAAAAAA (harness ws poison) and != 0 (fresh alloc).

#define B_DIM 512
#define N_DIM 2048
#define E_DIM 256
#define MAGIC 0x13C0FFEEu

typedef __attribute__((ext_vector_type(8))) __bf16 bf16x8;
typedef __attribute__((ext_vector_type(4))) float f32x4;

__device__ inline ushort f2bf(float x) {
    __hip_bfloat16 h = __float2bfloat16(x);   // RNE
    union { __hip_bfloat16 b; ushort u; } cv; cv.b = h; return cv.u;
}

__device__ inline float wave_sum(float v) {
#pragma unroll
    for (int m = 1; m < 64; m <<= 1) v += __shfl_xor(v, m, 64);
    return v;
}

// ws layout: Aws (32 groups * 16 steps * 64 slots * 8 ush = 512 KB)
//            cvec (512 f32), flags (32 u32)
__global__ __launch_bounds__(256) void pairre_fused1(
        const float* __restrict__ head, const float* __restrict__ tail,
        const float* __restrict__ rel,  const int* __restrict__ rid,
        ushort* __restrict__ Aws, float* __restrict__ cvec,
        unsigned* __restrict__ flags, float* __restrict__ out) {
    __shared__ ushort Tsq[32 * 64 * 8];    // [4 grp][8 s][64 slot][8]  32 KB
    __shared__ ushort Tli[32 * 64 * 8];    // 32 KB
    __shared__ float invt_s[64];
    __shared__ float invh_s[16];

    const int tid = threadIdx.x, lane = tid & 63, wv = tid >> 6;
    const int bid = blockIdx.x;
    const int p_b = bid & 15, p_n = bid >> 4;     // 16 x 32 tile grid

    // ---------- producers: blocks 0..31 build A-group g=bid ----------
    if (bid < 32) {
        const int g = bid;
        // P1: invh + cvec for 16 rows (wave: 4 rows)
#pragma unroll
        for (int j = 0; j < 4; ++j) {
            const int rl = wv * 4 + j;
            const int b = g * 16 + rl;
            const int id = rid[b];
            const float4 h4 = *(const float4*)(head + (size_t)b * E_DIM + lane * 4);
            const float4 r4 = *(const float4*)(rel + (size_t)id * 512 + lane * 4);
            const float s1 = wave_sum(h4.x*h4.x + h4.y*h4.y + h4.z*h4.z + h4.w*h4.w);
            const float inv = 1.0f / fmaxf(sqrtf(s1), 1e-12f);
            const float p0 = h4.x*inv*r4.x, p1 = h4.y*inv*r4.y,
                        p2 = h4.z*inv*r4.z, p3 = h4.w*inv*r4.w;
            const float s2 = wave_sum(p0*p0 + p1*p1 + p2*p2 + p3*p3);
            if (lane == 0) { invh_s[rl] = inv; cvec[b] = s2; }
        }
        __syncthreads();
        // P2: 1024 16B-chunks -> packed frags ((g*16+s)*64+slot)*8
#pragma unroll
        for (int k = 0; k < 4; ++k) {
            const int c = tid + k * 256;
            const int s = c >> 6, slot = c & 63;
            const int q = slot >> 4, mloc = slot & 15;
            const int b = g * 16 + mloc;
            const int id = rid[b];
            const float* rrow = rel + (size_t)id * 512;
            float v[8];
            if (s < 8) {                       // sq region: rt^2
                const int e = s * 32 + q * 8;
                const float4 a = *(const float4*)(rrow + E_DIM + e);
                const float4 bq = *(const float4*)(rrow + E_DIM + e + 4);
                const float rt[8] = {a.x,a.y,a.z,a.w,bq.x,bq.y,bq.z,bq.w};
#pragma unroll
                for (int j = 0; j < 8; ++j) v[j] = rt[j] * rt[j];
            } else {                           // lin region: -2*rt*Hh
                const int e = (s - 8) * 32 + q * 8;
                const float4 a = *(const float4*)(rrow + E_DIM + e);
                const float4 bq = *(const float4*)(rrow + E_DIM + e + 4);
                const float4 h0 = *(const float4*)(head + (size_t)b * E_DIM + e);
                const float4 h1 = *(const float4*)(head + (size_t)b * E_DIM + e + 4);
                const float4 r0 = *(const float4*)(rrow + e);
                const float4 r1 = *(const float4*)(rrow + e + 4);
                const float rt[8] = {a.x,a.y,a.z,a.w,bq.x,bq.y,bq.z,bq.w};
                const float hh[8] = {h0.x,h0.y,h0.z,h0.w,h1.x,h1.y,h1.z,h1.w};
                const float rr[8] = {r0.x,r0.y,r0.z,r0.w,r1.x,r1.y,r1.z,r1.w};
                const float inv = invh_s[mloc];
#pragma unroll
                for (int j = 0; j < 8; ++j) v[j] = -2.0f * rt[j] * (hh[j] * inv * rr[j]);
            }
            ushort u[8];
#pragma unroll
            for (int j = 0; j < 8; ++j) u[j] = f2bf(v[j]);
            *(uint4*)(Aws + ((size_t)(g * 16 + s) * 64 + slot) * 8) = *(const uint4*)u;
        }
        __threadfence();                      // release stores to agent scope
        __syncthreads();
        if (tid == 0)
            __hip_atomic_store(&flags[g], MAGIC, __ATOMIC_RELEASE,
                               __HIP_MEMORY_SCOPE_AGENT);
    }

    // ---------- tail staging: raw t -> LDS bf16 frags [t^2 | t] ----------
    {
        const int mloc = lane >> 2, q4 = lane & 3;
        const int rowg = p_n * 64 + wv * 16 + mloc;
        const float* trow = tail + (size_t)rowg * E_DIM;
        const int slot = q4 * 16 + mloc;
        float ss = 0.f;
#pragma unroll
        for (int s = 0; s < 8; ++s) {
            const int e = s * 32 + q4 * 8;
            const float4 a = *(const float4*)(trow + e);
            const float4 b = *(const float4*)(trow + e + 4);
            const float v[8] = {a.x,a.y,a.z,a.w,b.x,b.y,b.z,b.w};
            ushort us[8], ul[8];
#pragma unroll
            for (int j = 0; j < 8; ++j) {
                ss += v[j] * v[j];
                us[j] = f2bf(v[j] * v[j]);
                ul[j] = f2bf(v[j]);
            }
            *(uint4*)&Tsq[((wv * 8 + s) * 64 + slot) * 8] = *(const uint4*)us;
            *(uint4*)&Tli[((wv * 8 + s) * 64 + slot) * 8] = *(const uint4*)ul;
        }
        ss += __shfl_xor(ss, 1, 64);
        ss += __shfl_xor(ss, 2, 64);
        if (q4 == 0) invt_s[wv * 16 + mloc] = 1.0f / fmaxf(sqrtf(ss), 1e-12f);
    }

    // ---------- acquire A-group ----------
    const int wb = wv & 1, wn = wv >> 1;
    const int gA = p_b * 2 + wb;
    {
        int guard = 0;
        while (__hip_atomic_load(&flags[gA], __ATOMIC_ACQUIRE,
                                 __HIP_MEMORY_SCOPE_AGENT) != MAGIC) {
            __builtin_amdgcn_s_sleep(2);
            if (++guard > (1 << 26)) break;   // fail-visible, never hang
        }
    }
    __syncthreads();   // T-LDS visible block-wide; all waves have their A

    // ---------- MFMA: wave tile 16b x 32n, split sq/lin accumulators ----------
    const ushort* Ab = Aws + ((size_t)(gA * 16) * 64 + lane) * 8;  // + s*512
    const int g0 = 2 * wn, g1 = 2 * wn + 1;
    f32x4 aS0 = {0,0,0,0}, aS1 = {0,0,0,0}, aL0 = {0,0,0,0}, aL1 = {0,0,0,0};
#pragma unroll
    for (int s = 0; s < 8; ++s) {
        const bf16x8 asq = *(const bf16x8*)(Ab + (size_t)s * 512);
        const bf16x8 ali = *(const bf16x8*)(Ab + (size_t)(8 + s) * 512);
        const bf16x8 tq0 = *(const bf16x8*)&Tsq[((g0 * 8 + s) * 64 + lane) * 8];
        const bf16x8 tq1 = *(const bf16x8*)&Tsq[((g1 * 8 + s) * 64 + lane) * 8];
        const bf16x8 tl0 = *(const bf16x8*)&Tli[((g0 * 8 + s) * 64 + lane) * 8];
        const bf16x8 tl1 = *(const bf16x8*)&Tli[((g1 * 8 + s) * 64 + lane) * 8];
        aS0 = __builtin_amdgcn_mfma_f32_16x16x32_bf16(asq, tq0, aS0, 0, 0, 0);
        aS1 = __builtin_amdgcn_mfma_f32_16x16x32_bf16(asq, tq1, aS1, 0, 0, 0);
        aL0 = __builtin_amdgcn_mfma_f32_16x16x32_bf16(ali, tl0, aL0, 0, 0, 0);
        aL1 = __builtin_amdgcn_mfma_f32_16x16x32_bf16(ali, tl1, aL1, 0, 0, 0);
    }

    // ---------- epilogue: x = S1*invt^2 + S2*invt + c_b ----------
    const int ml = lane & 15, qq = lane >> 4;
    const float it0 = invt_s[wn * 32 + ml];
    const float it1 = invt_s[wn * 32 + 16 + ml];
    const int nb = p_n * 64 + wn * 32;
#pragma unroll
    for (int r = 0; r < 4; ++r) {
        const int b = p_b * 32 + wb * 16 + qq * 4 + r;
        const float cb = cvec[b];
        const float x0 = aS0[r] * it0 * it0 + aL0[r] * it0 + cb;
        const float x1 = aS1[r] * it1 * it1 + aL1[r] * it1 + cb;
        out[(size_t)b * N_DIM + nb + ml]      = -sqrtf(fmaxf(x0, 0.f));
        out[(size_t)b * N_DIM + nb + 16 + ml] = -sqrtf(fmaxf(x1, 0.f));
    }
}

// ---------------- fallback (ws too small): pure fp32 ----------------
__device__ inline float block_reduce_sum_256(float v, float* buf) {
#pragma unroll
    for (int o = 32; o > 0; o >>= 1) v += __shfl_down(v, o, 64);
    const int lane = threadIdx.x & 63, wid = threadIdx.x >> 6;
    __syncthreads();
    if (lane == 0) buf[wid] = v;
    __syncthreads();
    return buf[0] + buf[1] + buf[2] + buf[3];
}

__global__ __launch_bounds__(256) void fallback_kernel(
        const float* __restrict__ head, const float* __restrict__ tail,
        const float* __restrict__ rel,  const int* __restrict__ rid,
        float* __restrict__ out) {
    __shared__ float Hh[E_DIM];
    __shared__ float RT[E_DIM];
    __shared__ float buf[4];
    const int b = blockIdx.x;
    const int tid = threadIdx.x;
    const float hv = head[(size_t)b * E_DIM + tid];
    const int id = rid[b];
    const float rh = rel[(size_t)id * 512 + tid];
    const float rt = rel[(size_t)id * 512 + E_DIM + tid];
    const float tot = block_reduce_sum_256(hv * hv, buf);
    const float inv = 1.0f / fmaxf(sqrtf(tot), 1e-12f);
    const float HhV = hv * inv * rh;
    Hh[tid] = HhV; RT[tid] = rt;
    const float c = block_reduce_sum_256(HhV * HhV, buf);
    __syncthreads();
    for (int n = tid; n < N_DIM; n += 256) {
        float S1 = 0.f, S2 = 0.f, Stt = 0.f;
        for (int e = 0; e < E_DIM; ++e) {
            const float tv = tail[(size_t)n * E_DIM + e];
            const float p = tv * RT[e];
            S1 += p * p; S2 += p * Hh[e]; Stt += tv * tv;
        }
        const float al = 1.0f / fmaxf(sqrtf(Stt), 1e-12f);
        const float x = al * al * S1 - 2.0f * al * S2 + c;
        out[(size_t)b * N_DIM + n] = -sqrtf(fmaxf(x, 0.f));
    }
}

extern "C" void kernel_launch(void* const* d_in, const int* in_sizes, int n_in,
                              void* d_out, int out_size, void* d_ws, size_t ws_size,
                              hipStream_t stream) {
    const float* head = (const float*)d_in[0];
    const float* tail = (const float*)d_in[1];
    const float* rel  = (const float*)d_in[2];
    const int*   rid  = (const int*)d_in[3];
    float* out = (float*)d_out;

    const size_t aBytes = (size_t)32 * 16 * 64 * 8 * sizeof(ushort);  // 512 KB
    const size_t need = aBytes + 512 * sizeof(float) + 32 * sizeof(unsigned);
    if (ws_size >= need) {
        ushort* Aws = (ushort*)d_ws;
        float* cvec = (float*)((char*)d_ws + aBytes);
        unsigned* flags = (unsigned*)(cvec + 512);
        pairre_fused1<<<512, 256, 0, stream>>>(head, tail, rel, rid,
                                               Aws, cvec, flags, out);
    } else {
        fallback_kernel<<<B_DIM, 256, 0, stream>>>(head, tail, rel, rid, out);
    }
}

// Round 8
// 93.878 us; speedup vs baseline: 1.9564x; 1.9564x over previous
//
#include <hip/hip_runtime.h>
#include <hip/hip_bf16.h>

// PairRE scoring: out[b,n] = -|| t_hat[n]*rt[b] - h_hat[b]*rh[b] ||_2
// B=512, N=2048, E=256.
//
// Scale-invariant reformulation (R7-verified):
//   S1(b,n) = sum_e (rt^2)_b[e] * (t^2)_n[e]
//   S2(b,n) = sum_e (-2*rt*Hh)_b[e] * t_n[e],   Hh = (h/||h||)*rh
//   x = S1*invt^2 + S2*invt + c_b,  invt = 1/max(||t||,eps), c_b = ||Hh_b||^2
//   out = -sqrt(max(x,0))
//
// R8: ONE ordinary kernel, ZERO cross-block communication (R6/R7 lesson:
// grid.sync and flag handoffs are poison here). 1024 blocks = 32(b) x 32(n)
// tiles; each block redundantly builds its A-side (32 rows, x64 redundancy
// ~= 2.8us chip-wide L2 + ~1us VALU — cheaper than a second graph node
// ~10us) and its T-side locally in LDS, then 16 MFMAs/wave + epilogue.
// All fragment layouts identical to R7 (passed, absmax 7.8e-3).

#define B_DIM 512
#define N_DIM 2048
#define E_DIM 256

typedef __attribute__((ext_vector_type(8))) __bf16 bf16x8;
typedef __attribute__((ext_vector_type(4))) float f32x4;

__device__ inline ushort f2bf(float x) {
    __hip_bfloat16 h = __float2bfloat16(x);   // RNE
    union { __hip_bfloat16 b; ushort u; } cv; cv.b = h; return cv.u;
}

__device__ inline float wave_sum(float v) {
#pragma unroll
    for (int m = 1; m < 64; m <<= 1) v += __shfl_xor(v, m, 64);
    return v;
}

__global__ __launch_bounds__(256) void pairre_single(
        const float* __restrict__ head, const float* __restrict__ tail,
        const float* __restrict__ rel,  const int* __restrict__ rid,
        float* __restrict__ out) {
    __shared__ ushort Alds[2 * 16 * 64 * 8];   // 32 KB: [grp][s 0..15][slot][8]
    __shared__ ushort Tsq[2 * 8 * 64 * 8];     // 16 KB: t^2 frags
    __shared__ ushort Tli[2 * 8 * 64 * 8];     // 16 KB: t frags
    __shared__ float invh_s[32];
    __shared__ float cb_s[32];
    __shared__ float invt_s[32];

    const int tid = threadIdx.x, lane = tid & 63, wv = tid >> 6;
    const int bid = blockIdx.x;
    const int p_b = bid & 15, p_n = bid >> 4;   // 16 x 64 tile grid
    const int b0 = p_b * 32, n0 = p_n * 32;

    // ---- P1: head-side norms + cvec, 8 rows per wave (coalesced 1KB/row) ----
#pragma unroll
    for (int j = 0; j < 8; ++j) {
        const int rl = wv * 8 + j;
        const int b = b0 + rl;
        const int id = rid[b];
        const float4 h4 = *(const float4*)(head + (size_t)b * E_DIM + lane * 4);
        const float4 r4 = *(const float4*)(rel + (size_t)id * 512 + lane * 4);
        const float s1 = wave_sum(h4.x*h4.x + h4.y*h4.y + h4.z*h4.z + h4.w*h4.w);
        const float inv = 1.0f / fmaxf(sqrtf(s1), 1e-12f);
        const float p0 = h4.x*inv*r4.x, p1 = h4.y*inv*r4.y,
                    p2 = h4.z*inv*r4.z, p3 = h4.w*inv*r4.w;
        const float s2 = wave_sum(p0*p0 + p1*p1 + p2*p2 + p3*p3);
        if (lane == 0) { invh_s[rl] = inv; cb_s[rl] = s2; }
    }

    // ---- T staging: 8 rows/wave, raw t -> bf16 frags [t^2][t] ----
    {
        const int q8 = lane & 7, roct = lane >> 3;       // k-octant, row-in-octet
        const int rloc = wv * 8 + roct;                  // 0..31 local n-row
        const int grp = rloc >> 4, mloc = rloc & 15;
        const float* trow = tail + (size_t)(n0 + rloc) * E_DIM;
        float ss = 0.f;
#pragma unroll
        for (int s = 0; s < 4; ++s) {
            const int c = s * 8 + q8;                    // chunk 0..31
            const int e = c * 8;
            const float4 a = *(const float4*)(trow + e);
            const float4 b2 = *(const float4*)(trow + e + 4);
            const float v[8] = {a.x,a.y,a.z,a.w,b2.x,b2.y,b2.z,b2.w};
            ushort us[8], ul[8];
#pragma unroll
            for (int j = 0; j < 8; ++j) {
                ss += v[j] * v[j];
                us[j] = f2bf(v[j] * v[j]);
                ul[j] = f2bf(v[j]);
            }
            const int s32 = c >> 2, q = c & 3, slot = q * 16 + mloc;
            *(uint4*)&Tsq[((grp * 8 + s32) * 64 + slot) * 8] = *(const uint4*)us;
            *(uint4*)&Tli[((grp * 8 + s32) * 64 + slot) * 8] = *(const uint4*)ul;
        }
        ss += __shfl_xor(ss, 1, 64);
        ss += __shfl_xor(ss, 2, 64);
        ss += __shfl_xor(ss, 4, 64);
        if (q8 == 0) invt_s[rloc] = 1.0f / fmaxf(sqrtf(ss), 1e-12f);
    }
    __syncthreads();   // invh_s ready for P2; T-LDS ready for MFMA

    // ---- P2: pack A-frags [rt^2 | -2*rt*Hh] into LDS (R7 producer body) ----
#pragma unroll
    for (int k = 0; k < 8; ++k) {
        const int c = tid + k * 256;          // 0..2047
        const int gloc = c >> 10;
        const int rem = c & 1023;
        const int s = rem >> 6;               // 0..15
        const int slot = rem & 63;
        const int q = slot >> 4, mloc = slot & 15;
        const int rl = gloc * 16 + mloc;
        const int b = b0 + rl;
        const int id = rid[b];
        const float* rrow = rel + (size_t)id * 512;
        float v[8];
        if (s < 8) {                          // sq region: rt^2
            const int e = s * 32 + q * 8;
            const float4 a = *(const float4*)(rrow + E_DIM + e);
            const float4 bq = *(const float4*)(rrow + E_DIM + e + 4);
            const float rt[8] = {a.x,a.y,a.z,a.w,bq.x,bq.y,bq.z,bq.w};
#pragma unroll
            for (int j = 0; j < 8; ++j) v[j] = rt[j] * rt[j];
        } else {                              // lin region: -2*rt*Hh
            const int e = (s - 8) * 32 + q * 8;
            const float4 a = *(const float4*)(rrow + E_DIM + e);
            const float4 bq = *(const float4*)(rrow + E_DIM + e + 4);
            const float4 h0 = *(const float4*)(head + (size_t)b * E_DIM + e);
            const float4 h1 = *(const float4*)(head + (size_t)b * E_DIM + e + 4);
            const float4 r0 = *(const float4*)(rrow + e);
            const float4 r1 = *(const float4*)(rrow + e + 4);
            const float rt[8] = {a.x,a.y,a.z,a.w,bq.x,bq.y,bq.z,bq.w};
            const float hh[8] = {h0.x,h0.y,h0.z,h0.w,h1.x,h1.y,h1.z,h1.w};
            const float rr[8] = {r0.x,r0.y,r0.z,r0.w,r1.x,r1.y,r1.z,r1.w};
            const float inv = invh_s[rl];
#pragma unroll
            for (int j = 0; j < 8; ++j) v[j] = -2.0f * rt[j] * (hh[j] * inv * rr[j]);
        }
        ushort u[8];
#pragma unroll
        for (int j = 0; j < 8; ++j) u[j] = f2bf(v[j]);
        *(uint4*)&Alds[((gloc * 16 + s) * 64 + slot) * 8] = *(const uint4*)u;
    }
    __syncthreads();

    // ---- MFMA: wave (wb, wn) -> 16b x 16n, split sq/lin accumulators ----
    const int wb = wv & 1, wn = wv >> 1;
    f32x4 aS = {0.f,0.f,0.f,0.f}, aL = {0.f,0.f,0.f,0.f};
#pragma unroll
    for (int s = 0; s < 8; ++s) {
        const bf16x8 asq = *(const bf16x8*)&Alds[((wb * 16 + s) * 64 + lane) * 8];
        const bf16x8 ali = *(const bf16x8*)&Alds[((wb * 16 + 8 + s) * 64 + lane) * 8];
        const bf16x8 tq  = *(const bf16x8*)&Tsq[((wn * 8 + s) * 64 + lane) * 8];
        const bf16x8 tl  = *(const bf16x8*)&Tli[((wn * 8 + s) * 64 + lane) * 8];
        aS = __builtin_amdgcn_mfma_f32_16x16x32_bf16(asq, tq, aS, 0, 0, 0);
        aL = __builtin_amdgcn_mfma_f32_16x16x32_bf16(ali, tl, aL, 0, 0, 0);
    }

    // ---- epilogue: x = S1*invt^2 + S2*invt + c_b ----
    const int ml = lane & 15, q = lane >> 4;
    const float it = invt_s[wn * 16 + ml];
    const int nn = n0 + wn * 16 + ml;
#pragma unroll
    for (int r = 0; r < 4; ++r) {
        const int rl = wb * 16 + q * 4 + r;
        const int b = b0 + rl;
        const float x = aS[r] * it * it + aL[r] * it + cb_s[rl];
        out[(size_t)b * N_DIM + nn] = -sqrtf(fmaxf(x, 0.f));
    }
}

extern "C" void kernel_launch(void* const* d_in, const int* in_sizes, int n_in,
                              void* d_out, int out_size, void* d_ws, size_t ws_size,
                              hipStream_t stream) {
    const float* head = (const float*)d_in[0];
    const float* tail = (const float*)d_in[1];
    const float* rel  = (const float*)d_in[2];
    const int*   rid  = (const int*)d_in[3];
    float* out = (float*)d_out;
    (void)d_ws; (void)ws_size;

    pairre_single<<<1024, 256, 0, stream>>>(head, tail, rel, rid, out);
}

// Round 9
// 71.750 us; speedup vs baseline: 2.5598x; 1.3084x over previous
//
#include <hip/hip_runtime.h>
#include <hip/hip_bf16.h>

// PairRE scoring: out[b,n] = -|| t_hat[n]*rt[b] - h_hat[b]*rh[b] ||_2
// B=512, N=2048, E=256.
//
// x(b,n) = dot([T^2 | T]_n , [rt^2 | -2*rt*Hh]_b) + c_b,
//   T = t/||t||, Hh = (h/||h||)*rh, c_b = ||Hh_b||^2.
//
// R9 = R4 prep (verbatim, verified) + higher-TLP score:
//  score: per-wave 16(b) x 16(n) tile, 1024 blocks x 4 waves = 4096 waves
//  = 16 waves/CU (4/SIMD; R4 had 2/SIMD). Block = 2x2 wave grid over
//  {2 A-groups} x {2 T-groups} -> each fragment stream read twice -> L1 dedup.
//  No LDS, no barriers; 16-step software-pipelined MFMA chain.
// Lessons baked in: no cross-block deps (R6/R7), no fused redundant prep (R8),
// packed-fragment coalesced loads only (R5).

#define B_DIM 512
#define N_DIM 2048
#define E_DIM 256
#define K_DIM 512
#define NSTEP 16        // K/32 MFMA k-steps
#define FRAG_US 512     // ushorts per packed fragment (64 lanes * 8)

typedef __attribute__((ext_vector_type(8))) __bf16 bf16x8;
typedef __attribute__((ext_vector_type(4))) float f32x4;

__device__ inline ushort f2bf(float x) {
    __hip_bfloat16 h = __float2bfloat16(x);   // RNE
    union { __hip_bfloat16 b; ushort u; } cv; cv.b = h; return cv.u;
}

__device__ inline float wave_sum(float v) {
#pragma unroll
    for (int m = 1; m < 64; m <<= 1) v += __shfl_xor(v, m, 64);
    return v;
}

// ---------------- prep: wave-per-row, packed-fragment bf16 operands ----------------
// (R4 verbatim) Packed addr for row r=g*16+m, k=c*8+j (c=s*4+q):
//   dst=((g*16+s)*64+q*16+m)*8 ; lane writes k0=lane*8 -> s=lane>>2, q=lane&3.
__global__ __launch_bounds__(256) void prep_kernel(
        const float* __restrict__ head, const float* __restrict__ tail,
        const float* __restrict__ rel,  const int* __restrict__ rid,
        ushort* __restrict__ Tbig, ushort* __restrict__ Abig,
        float* __restrict__ cvec) {
    const int tid = threadIdx.x, lane = tid & 63, wv = tid >> 6;
    const int w = blockIdx.x * 4 + wv;     // 0..2559
    const int s_ = lane >> 2, q = lane & 3;
    const int k0 = lane * 8;
    const bool sqr = (k0 < E_DIM);
    const int e0 = k0 & (E_DIM - 1);

    if (w < N_DIM) {
        const int n = w;
        const float* row = tail + (size_t)n * E_DIM;
        const float4 v4 = ((const float4*)row)[lane];
        const float s = wave_sum(v4.x * v4.x + v4.y * v4.y + v4.z * v4.z + v4.w * v4.w);
        const float inv = 1.0f / fmaxf(sqrtf(s), 1e-12f);
        const float4 f0 = *(const float4*)(row + e0);
        const float4 f1 = *(const float4*)(row + e0 + 4);
        const float v[8] = {f0.x, f0.y, f0.z, f0.w, f1.x, f1.y, f1.z, f1.w};
        ushort u[8];
#pragma unroll
        for (int j = 0; j < 8; ++j) {
            float x = v[j] * inv;
            if (sqr) x *= x;
            u[j] = f2bf(x);
        }
        const int g = n >> 4, m = n & 15;
        *(uint4*)(Tbig + (size_t)((g * 16 + s_) * 64 + q * 16 + m) * 8) = *(const uint4*)u;
    } else {
        const int b = w - N_DIM;
        const int id = rid[b];
        const float* hrow  = head + (size_t)b * E_DIM;
        const float* rhrow = rel + (size_t)id * (2 * E_DIM);
        const float* rtrow = rhrow + E_DIM;
        const float4 h4  = ((const float4*)hrow)[lane];
        const float4 rh4 = ((const float4*)rhrow)[lane];
        const float s1 = wave_sum(h4.x * h4.x + h4.y * h4.y + h4.z * h4.z + h4.w * h4.w);
        const float inv = 1.0f / fmaxf(sqrtf(s1), 1e-12f);
        const float p0 = h4.x * inv * rh4.x, p1 = h4.y * inv * rh4.y;
        const float p2 = h4.z * inv * rh4.z, p3 = h4.w * inv * rh4.w;
        const float s2 = wave_sum(p0 * p0 + p1 * p1 + p2 * p2 + p3 * p3);
        if (lane == 0) cvec[b] = s2;

        const float4 rt0 = *(const float4*)(rtrow + e0);
        const float4 rt1 = *(const float4*)(rtrow + e0 + 4);
        const float rt[8] = {rt0.x, rt0.y, rt0.z, rt0.w, rt1.x, rt1.y, rt1.z, rt1.w};
        float v[8];
        if (sqr) {
#pragma unroll
            for (int j = 0; j < 8; ++j) v[j] = rt[j] * rt[j];
        } else {
            const float4 h0 = *(const float4*)(hrow + e0);
            const float4 h1 = *(const float4*)(hrow + e0 + 4);
            const float4 r0 = *(const float4*)(rhrow + e0);
            const float4 r1 = *(const float4*)(rhrow + e0 + 4);
            const float hh[8] = {h0.x, h0.y, h0.z, h0.w, h1.x, h1.y, h1.z, h1.w};
            const float rr[8] = {r0.x, r0.y, r0.z, r0.w, r1.x, r1.y, r1.z, r1.w};
#pragma unroll
            for (int j = 0; j < 8; ++j) v[j] = -2.0f * rt[j] * (hh[j] * inv * rr[j]);
        }
        ushort u[8];
#pragma unroll
        for (int j = 0; j < 8; ++j) u[j] = f2bf(v[j]);
        const int g = b >> 4, m = b & 15;
        *(uint4*)(Abig + (size_t)((g * 16 + s_) * 64 + q * 16 + m) * 8) = *(const uint4*)u;
    }
}

// ---------------- score: 16x16 per wave, 4096 waves (4/SIMD) ----------------
// grid 1024: pb = bid&15 (A super-group: rows pb*32..+31), pn = bid>>4
// (T super-group: cols pn*32..+31). Wave (wb=wv&1, wn=wv>>1):
//   gA = pb*2+wb, gT = pn*2+wn. Each stream read by 2 waves -> L1 dedup.
__global__ __launch_bounds__(256, 4) void score_kernel(
        const ushort* __restrict__ Tbig, const ushort* __restrict__ Abig,
        const float* __restrict__ cvec, float* __restrict__ out) {
    const int tid = threadIdx.x, lane = tid & 63, wv = tid >> 6;
    const int bid = blockIdx.x;
    const int pb = bid & 15, pn = bid >> 4;
    const int gA = pb * 2 + (wv & 1);
    const int gT = pn * 2 + (wv >> 1);

    const ushort* Ab = Abig + (size_t)gA * NSTEP * FRAG_US + lane * 8;
    const ushort* Tb = Tbig + (size_t)gT * NSTEP * FRAG_US + lane * 8;

    f32x4 acc = {0.f, 0.f, 0.f, 0.f};
    bf16x8 a_c = *(const bf16x8*)(Ab);
    bf16x8 t_c = *(const bf16x8*)(Tb);
#pragma unroll
    for (int s = 0; s < NSTEP - 1; ++s) {
        const bf16x8 a_n = *(const bf16x8*)(Ab + (s + 1) * FRAG_US);
        const bf16x8 t_n = *(const bf16x8*)(Tb + (s + 1) * FRAG_US);
        acc = __builtin_amdgcn_mfma_f32_16x16x32_bf16(a_c, t_c, acc, 0, 0, 0);
        a_c = a_n; t_c = t_n;
    }
    acc = __builtin_amdgcn_mfma_f32_16x16x32_bf16(a_c, t_c, acc, 0, 0, 0);

    const int ml = lane & 15, q = lane >> 4;
    const int n_idx = gT * 16 + ml;
#pragma unroll
    for (int r = 0; r < 4; ++r) {
        const int b = gA * 16 + q * 4 + r;
        out[(size_t)b * N_DIM + n_idx] = -sqrtf(fmaxf(acc[r] + cvec[b], 0.f));
    }
}

// ---------------- fallback (no workspace): pure fp32 ----------------
__device__ inline float block_reduce_sum_256(float v, float* buf) {
#pragma unroll
    for (int o = 32; o > 0; o >>= 1) v += __shfl_down(v, o, 64);
    const int lane = threadIdx.x & 63, wid = threadIdx.x >> 6;
    __syncthreads();
    if (lane == 0) buf[wid] = v;
    __syncthreads();
    return buf[0] + buf[1] + buf[2] + buf[3];
}

__global__ __launch_bounds__(256) void fallback_kernel(
        const float* __restrict__ head, const float* __restrict__ tail,
        const float* __restrict__ rel,  const int* __restrict__ rid,
        float* __restrict__ out) {
    __shared__ float Hh[E_DIM];
    __shared__ float RT[E_DIM];
    __shared__ float buf[4];
    const int b = blockIdx.x;
    const int tid = threadIdx.x;
    const float hv = head[(size_t)b * E_DIM + tid];
    const int id = rid[b];
    const float rh = rel[(size_t)id * 512 + tid];
    const float rt = rel[(size_t)id * 512 + E_DIM + tid];
    const float tot = block_reduce_sum_256(hv * hv, buf);
    const float inv = 1.0f / fmaxf(sqrtf(tot), 1e-12f);
    const float HhV = hv * inv * rh;
    Hh[tid] = HhV; RT[tid] = rt;
    const float c = block_reduce_sum_256(HhV * HhV, buf);
    __syncthreads();
    for (int n = tid; n < N_DIM; n += 256) {
        float S1 = 0.f, S2 = 0.f, Stt = 0.f;
        for (int e = 0; e < E_DIM; ++e) {
            const float tv = tail[(size_t)n * E_DIM + e];
            const float p = tv * RT[e];
            S1 += p * p; S2 += p * Hh[e]; Stt += tv * tv;
        }
        const float al = 1.0f / fmaxf(sqrtf(Stt), 1e-12f);
        const float x = al * al * S1 - 2.0f * al * S2 + c;
        out[(size_t)b * N_DIM + n] = -sqrtf(fmaxf(x, 0.f));
    }
}

extern "C" void kernel_launch(void* const* d_in, const int* in_sizes, int n_in,
                              void* d_out, int out_size, void* d_ws, size_t ws_size,
                              hipStream_t stream) {
    const float* head = (const float*)d_in[0];
    const float* tail = (const float*)d_in[1];
    const float* rel  = (const float*)d_in[2];
    const int*   rid  = (const int*)d_in[3];
    float* out = (float*)d_out;

    const size_t needT = (size_t)N_DIM * K_DIM * sizeof(ushort);   // 2 MB
    const size_t needA = (size_t)B_DIM * K_DIM * sizeof(ushort);   // 512 KB
    const size_t needC = (size_t)B_DIM * sizeof(float);            // 2 KB
    if (ws_size >= needT + needA + needC) {
        ushort* Tbig = (ushort*)d_ws;
        ushort* Abig = Tbig + (size_t)N_DIM * K_DIM;
        float*  cvec = (float*)(Abig + (size_t)B_DIM * K_DIM);
        prep_kernel<<<(N_DIM + B_DIM) / 4, 256, 0, stream>>>(head, tail, rel, rid,
                                                             Tbig, Abig, cvec);
        score_kernel<<<1024, 256, 0, stream>>>(Tbig, Abig, cvec, out);
    } else {
        fallback_kernel<<<B_DIM, 256, 0, stream>>>(head, tail, rel, rid, out);
    }
}